// Round 1
// baseline (1525.155 us; speedup 1.0000x reference)
//
#include <hip/hip_runtime.h>
#include <cstddef>

#define NS 256      // B*K samples
#define NF 256      // FEATURE_DIM
#define NC1 16
#define NC2 32
#define FCHUNK 32   // features per adjoint chunk

// ---------------------------------------------------------------------------
// 1-D bilinear profiles of the rectangle indicators (half-pixel centers).
// For g >= 100 the sample coord u=(j+0.5)*g/100-0.5 lies in [0, g-1]: interior.
__global__ __launch_bounds__(256) void k_profiles(
    const int* __restrict__ obx, const int* __restrict__ oby,
    const int* __restrict__ obw, const int* __restrict__ obh,
    const int* __restrict__ ghp, const int* __restrict__ gwp,
    float* __restrict__ py, float* __restrict__ px,
    float* __restrict__ hy, float* __restrict__ hx) {
  int n = threadIdx.x;  // 0..255 = sample
  float gh = (float)ghp[0], gw = (float)gwp[0];
  float sy = gh / 100.0f, sx = gw / 100.0f;
  int x0 = obx[n], y0 = oby[n], w = obw[n], h = obh[n];
  for (int j = 0; j < 100; ++j) {
    float u = (j + 0.5f) * sx - 0.5f;
    int a0 = (int)floorf(u);
    float t = u - (float)a0;
    float v0 = (a0 >= x0 && a0 < x0 + w) ? 1.f : 0.f;
    float v1 = (a0 + 1 >= x0 && a0 + 1 < x0 + w) ? 1.f : 0.f;
    px[n * 100 + j] = (1.f - t) * v0 + t * v1;

    u = (j + 0.5f) * sy - 0.5f;
    a0 = (int)floorf(u);
    t = u - (float)a0;
    v0 = (a0 >= y0 && a0 < y0 + h) ? 1.f : 0.f;
    v1 = (a0 + 1 >= y0 && a0 + 1 < y0 + h) ? 1.f : 0.f;
    py[n * 100 + j] = (1.f - t) * v0 + t * v1;
  }
  if (n < 100) {
    int j = n;
    float u = (j + 0.5f) * sx - 0.5f;
    int a0 = (int)floorf(u);
    float t = u - (float)a0;
    float v0 = (a0 >= 0 && a0 < 100) ? 1.f : 0.f;
    float v1 = (a0 + 1 >= 0 && a0 + 1 < 100) ? 1.f : 0.f;
    hx[j] = (1.f - t) * v0 + t * v1;

    u = (j + 0.5f) * sy - 0.5f;
    a0 = (int)floorf(u);
    t = u - (float)a0;
    v0 = (a0 >= 0 && a0 < 100) ? 1.f : 0.f;
    v1 = (a0 + 1 >= 0 && a0 + 1 < 100) ? 1.f : 0.f;
    hy[j] = (1.f - t) * v0 + t * v1;
  }
}

// ---------------------------------------------------------------------------
// Forward pipeline on the (shared) human channel, WITH biases.
__global__ __launch_bounds__(256) void k_t1h(
    const float* __restrict__ w1, const float* __restrict__ b1,
    const float* __restrict__ hy, const float* __restrict__ hx,
    float* __restrict__ t1h) {
  int idx = blockIdx.x * 256 + threadIdx.x;  // c1*10000 + p
  if (idx >= NC1 * 10000) return;
  int c1 = idx / 10000, p = idx % 10000;
  int i = p / 100, j = p % 100;
  float acc = b1[c1];
  for (int dy = 0; dy < 3; ++dy) {
    int yy = i + dy - 1;
    if (yy < 0 || yy >= 100) continue;
    for (int dx = 0; dx < 3; ++dx) {
      int xx = j + dx - 1;
      if (xx < 0 || xx >= 100) continue;
      acc += w1[((c1 * 2 + 0) * 3 + dy) * 3 + dx] * hy[yy] * hx[xx];
    }
  }
  t1h[idx] = acc;
}

__global__ __launch_bounds__(256) void k_t2h(
    const float* __restrict__ w2, const float* __restrict__ b2,
    const float* __restrict__ t1h, float* __restrict__ t2h) {
  int idx = blockIdx.x * 256 + threadIdx.x;  // c2*10000 + p
  if (idx >= NC2 * 10000) return;
  int c2 = idx / 10000, p = idx % 10000;
  int i = p / 100, j = p % 100;
  float acc = b2[c2];
  for (int c1 = 0; c1 < NC1; ++c1)
    for (int dy = 0; dy < 3; ++dy) {
      int yy = i + dy - 1;
      if (yy < 0 || yy >= 100) continue;
      for (int dx = 0; dx < 3; ++dx) {
        int xx = j + dx - 1;
        if (xx < 0 || xx >= 100) continue;
        acc += w2[((c2 * NC1 + c1) * 3 + dy) * 3 + dx] *
               t1h[c1 * 10000 + yy * 100 + xx];
      }
    }
  t2h[idx] = acc;
}

__global__ __launch_bounds__(256) void k_initbase(
    const float* __restrict__ pb, float* __restrict__ base) {
  base[threadIdx.x] = pb[threadIdx.x];
}

// ---------------------------------------------------------------------------
// Adjoint of conv2 applied to proj rows P_f (reshaped 32x100x100), fused with
// base[f] += <P_f, t2h>. Reads proj_w exactly once per call across chunks.
// g1[f,c1,p] = sum_{c2,dy,dx} w2[c2,c1,dy,dx] * P[f,c2, p + (1-dy,1-dx)]
__global__ __launch_bounds__(256) void k_adj2(
    const float* __restrict__ P, const float* __restrict__ w2,
    const float* __restrict__ t2h, float* __restrict__ g1,
    float* __restrict__ base, int f0) {
  __shared__ float tile[18 * 18];
  __shared__ float red[256];
  int tid = threadIdx.x;
  int f = f0 + blockIdx.y;
  int fl = blockIdx.y;
  int tidx = blockIdx.x;  // 0..48 spatial tiles (7x7 of 16x16)
  int ty0 = (tidx / 7) * 16, tx0 = (tidx % 7) * 16;
  int ly = tid / 16, lx = tid % 16;
  int gy = ty0 + ly, gx = tx0 + lx;
  bool valid = (gy < 100 && gx < 100);
  float acc[NC1];
#pragma unroll
  for (int c = 0; c < NC1; ++c) acc[c] = 0.f;
  float bacc = 0.f;
  const size_t fbase = (size_t)f * (NC2 * 10000);

  for (int c2 = 0; c2 < NC2; ++c2) {
    __syncthreads();
    for (int i = tid; i < 324; i += 256) {
      int r = i / 18, c = i % 18;
      int yy = ty0 - 1 + r, xx = tx0 - 1 + c;
      float v = 0.f;
      if (yy >= 0 && yy < 100 && xx >= 0 && xx < 100)
        v = P[fbase + (size_t)c2 * 10000 + yy * 100 + xx];
      tile[i] = v;
    }
    __syncthreads();
    float v[3][3];
#pragma unroll
    for (int a = 0; a < 3; ++a)
#pragma unroll
      for (int b = 0; b < 3; ++b) v[a][b] = tile[(ly + a) * 18 + lx + b];
    if (valid) bacc += v[1][1] * t2h[c2 * 10000 + gy * 100 + gx];
#pragma unroll
    for (int c1 = 0; c1 < NC1; ++c1) {
      float a = acc[c1];
#pragma unroll
      for (int dy = 0; dy < 3; ++dy)
#pragma unroll
        for (int dx = 0; dx < 3; ++dx)
          a += w2[(c2 * NC1 + c1) * 9 + dy * 3 + dx] * v[2 - dy][2 - dx];
      acc[c1] = a;
    }
  }
  if (valid) {
#pragma unroll
    for (int c1 = 0; c1 < NC1; ++c1)
      g1[((size_t)(fl * NC1 + c1)) * 10000 + gy * 100 + gx] = acc[c1];
  }
  red[tid] = bacc;
  __syncthreads();
  for (int s = 128; s > 0; s >>= 1) {
    if (tid < s) red[tid] += red[tid + s];
    __syncthreads();
  }
  if (tid == 0) atomicAdd(&base[f], red[0]);
}

// Adjoint of conv1 restricted to the obj input channel (channel 1):
// G[f,p] = sum_{c1,dy,dx} w1[c1,1,dy,dx] * g1[f,c1, p + (1-dy,1-dx)]
__global__ __launch_bounds__(256) void k_adj1(
    const float* __restrict__ g1, const float* __restrict__ w1,
    float* __restrict__ G, int f0) {
  __shared__ float tile[18 * 18];
  int tid = threadIdx.x;
  int fl = blockIdx.y;
  int f = f0 + fl;
  int tidx = blockIdx.x;
  int ty0 = (tidx / 7) * 16, tx0 = (tidx % 7) * 16;
  int ly = tid / 16, lx = tid % 16;
  int gy = ty0 + ly, gx = tx0 + lx;
  bool valid = (gy < 100 && gx < 100);
  float acc = 0.f;
  for (int c1 = 0; c1 < NC1; ++c1) {
    __syncthreads();
    for (int i = tid; i < 324; i += 256) {
      int r = i / 18, c = i % 18;
      int yy = ty0 - 1 + r, xx = tx0 - 1 + c;
      float v = 0.f;
      if (yy >= 0 && yy < 100 && xx >= 0 && xx < 100)
        v = g1[((size_t)(fl * NC1 + c1)) * 10000 + yy * 100 + xx];
      tile[i] = v;
    }
    __syncthreads();
#pragma unroll
    for (int dy = 0; dy < 3; ++dy)
#pragma unroll
      for (int dx = 0; dx < 3; ++dx)
        acc += w1[((c1 * 2 + 1) * 3 + dy) * 3 + dx] *
               tile[(ly + 2 - dy) * 18 + lx + 2 - dx];
  }
  if (valid) G[(size_t)f * 10000 + gy * 100 + gx] = acc;
}

// ---------------------------------------------------------------------------
// M[p,n] = py[n,i]*px[n,j]  (rank-1 obj maps, n-fastest for coalescing)
__global__ __launch_bounds__(256) void k_buildM(
    const float* __restrict__ py, const float* __restrict__ px,
    float* __restrict__ M) {
  int p = blockIdx.x;  // 0..9999
  int n = threadIdx.x;
  int i = p / 100, j = p % 100;
  M[(size_t)p * 256 + n] = py[n * 100 + i] * px[n * 100 + j];
}

__global__ __launch_bounds__(256) void k_outinit(
    const float* __restrict__ base, float* __restrict__ out) {
  out[blockIdx.x * 256 + threadIdx.x] = base[threadIdx.x];
}

// out[n,f] += sum_p G[f,p] * M[p,n].  64x64 tiles, split-K 16, f32 atomics.
__global__ __launch_bounds__(256) void k_gemm(
    const float* __restrict__ G, const float* __restrict__ M,
    float* __restrict__ out) {
  int tf = threadIdx.x / 16, tn = threadIdx.x % 16;
  int f0 = blockIdx.x * 64 + tf * 4;
  int n0 = blockIdx.y * 64 + tn * 4;
  int k0 = blockIdx.z * 625, k1 = k0 + 625;
  float acc[4][4] = {};
  for (int k = k0; k < k1; ++k) {
    float g[4], m[4];
#pragma unroll
    for (int a = 0; a < 4; ++a) g[a] = G[(size_t)(f0 + a) * 10000 + k];
#pragma unroll
    for (int b = 0; b < 4; ++b) m[b] = M[(size_t)k * 256 + n0 + b];
#pragma unroll
    for (int a = 0; a < 4; ++a)
#pragma unroll
      for (int b = 0; b < 4; ++b) acc[a][b] += g[a] * m[b];
  }
#pragma unroll
  for (int a = 0; a < 4; ++a)
#pragma unroll
    for (int b = 0; b < 4; ++b)
      atomicAdd(&out[(size_t)(n0 + b) * 256 + f0 + a], acc[a][b]);
}

// ---------------------------------------------------------------------------
extern "C" void kernel_launch(void* const* d_in, const int* in_sizes, int n_in,
                              void* d_out, int out_size, void* d_ws,
                              size_t ws_size, hipStream_t stream) {
  const int* obj_x = (const int*)d_in[0];
  const int* obj_y = (const int*)d_in[1];
  const int* obj_w = (const int*)d_in[2];
  const int* obj_h = (const int*)d_in[3];
  const int* g_h = (const int*)d_in[4];
  const int* g_w = (const int*)d_in[5];
  const float* conv1_w = (const float*)d_in[6];
  const float* conv1_b = (const float*)d_in[7];
  const float* conv2_w = (const float*)d_in[8];
  const float* conv2_b = (const float*)d_in[9];
  const float* proj_w = (const float*)d_in[10];
  const float* proj_b = (const float*)d_in[11];
  float* out = (float*)d_out;

  float* w = (float*)d_ws;
  float* py = w;   w += NS * 100;
  float* px = w;   w += NS * 100;
  float* hy = w;   w += 100;
  float* hx = w;   w += 100;
  float* t1h = w;  w += NC1 * 10000;
  float* t2h = w;  w += NC2 * 10000;
  float* base = w; w += NF;
  float* G = w;    w += (size_t)NF * 10000;
  float* M = w;    w += (size_t)10000 * NS;
  float* g1 = w;   w += (size_t)FCHUNK * NC1 * 10000;
  // total ~10.77M floats = ~43.1 MB of ws

  k_profiles<<<1, 256, 0, stream>>>(obj_x, obj_y, obj_w, obj_h, g_h, g_w, py,
                                    px, hy, hx);
  k_t1h<<<625, 256, 0, stream>>>(conv1_w, conv1_b, hy, hx, t1h);
  k_t2h<<<1250, 256, 0, stream>>>(conv2_w, conv2_b, t1h, t2h);
  k_initbase<<<1, 256, 0, stream>>>(proj_b, base);
  for (int c = 0; c < NF / FCHUNK; ++c) {
    k_adj2<<<dim3(49, FCHUNK), 256, 0, stream>>>(proj_w, conv2_w, t2h, g1,
                                                 base, c * FCHUNK);
    k_adj1<<<dim3(49, FCHUNK), 256, 0, stream>>>(g1, conv1_w, G, c * FCHUNK);
  }
  k_buildM<<<10000, 256, 0, stream>>>(py, px, M);
  k_outinit<<<256, 256, 0, stream>>>(base, out);
  k_gemm<<<dim3(4, 4, 16), 256, 0, stream>>>(G, M, out);
}

// Round 2
// 993.100 us; speedup vs baseline: 1.5358x; 1.5358x over previous
//
#include <hip/hip_runtime.h>
#include <cstddef>

#define NS 256
#define NF 256
#define NC1 16
#define NC2 32

// ---------------------------------------------------------------------------
// prep: block 0 = 1-D bilinear profiles (transposed layout), block 1 = Weff
// (composed 5x5 adjoint kernel), block 2 = base init with proj_b.
__global__ __launch_bounds__(256) void k_prep(
    const int* __restrict__ obx, const int* __restrict__ oby,
    const int* __restrict__ obw, const int* __restrict__ obh,
    const int* __restrict__ ghp, const int* __restrict__ gwp,
    const float* __restrict__ w1, const float* __restrict__ w2,
    const float* __restrict__ pb,
    float* __restrict__ pyT, float* __restrict__ pxT,
    float* __restrict__ hy, float* __restrict__ hx,
    float* __restrict__ Weff, float* __restrict__ base) {
  int tid = threadIdx.x;
  if (blockIdx.x == 0) {
    int n = tid;
    float gh = (float)ghp[0], gw = (float)gwp[0];
    float sy = gh / 100.0f, sx = gw / 100.0f;
    int x0 = obx[n], y0 = oby[n], w = obw[n], h = obh[n];
    for (int j = 0; j < 100; ++j) {
      float u = (j + 0.5f) * sx - 0.5f;
      int a0 = (int)floorf(u);
      float t = u - (float)a0;
      float v0 = (a0 >= x0 && a0 < x0 + w) ? 1.f : 0.f;
      float v1 = (a0 + 1 >= x0 && a0 + 1 < x0 + w) ? 1.f : 0.f;
      pxT[j * 256 + n] = (1.f - t) * v0 + t * v1;
      u = (j + 0.5f) * sy - 0.5f;
      a0 = (int)floorf(u);
      t = u - (float)a0;
      v0 = (a0 >= y0 && a0 < y0 + h) ? 1.f : 0.f;
      v1 = (a0 + 1 >= y0 && a0 + 1 < y0 + h) ? 1.f : 0.f;
      pyT[j * 256 + n] = (1.f - t) * v0 + t * v1;
    }
    if (n < 100) {
      int j = n;
      float u = (j + 0.5f) * sx - 0.5f;
      int a0 = (int)floorf(u);
      float t = u - (float)a0;
      float v0 = (a0 >= 0 && a0 < 100) ? 1.f : 0.f;
      float v1 = (a0 + 1 >= 0 && a0 + 1 < 100) ? 1.f : 0.f;
      hx[j] = (1.f - t) * v0 + t * v1;
      u = (j + 0.5f) * sy - 0.5f;
      a0 = (int)floorf(u);
      t = u - (float)a0;
      v0 = (a0 >= 0 && a0 < 100) ? 1.f : 0.f;
      v1 = (a0 + 1 >= 0 && a0 + 1 < 100) ? 1.f : 0.f;
      hy[j] = (1.f - t) * v0 + t * v1;
    }
  } else if (blockIdx.x == 1) {
    for (int idx = tid; idx < NC2 * 25; idx += 256) {
      int c2 = idx / 25, d = idx % 25;
      int dy = d / 5, dx = d % 5;
      float s = 0.f;
      for (int c1 = 0; c1 < NC1; ++c1)
        for (int sy = 0; sy < 3; ++sy) {
          int ty = dy - sy;
          if (ty < 0 || ty > 2) continue;
          for (int sx = 0; sx < 3; ++sx) {
            int tx = dx - sx;
            if (tx < 0 || tx > 2) continue;
            s += w1[((c1 * 2 + 1) * 3 + (2 - sy)) * 3 + (2 - sx)] *
                 w2[((c2 * NC1 + c1) * 9 + (2 - ty) * 3 + (2 - tx))];
          }
        }
      Weff[idx] = s;
    }
  } else {
    base[tid] = pb[tid];
  }
}

// ---------------------------------------------------------------------------
// Forward human-channel pipeline (with biases).
__global__ __launch_bounds__(256) void k_t1h(
    const float* __restrict__ w1, const float* __restrict__ b1,
    const float* __restrict__ hy, const float* __restrict__ hx,
    float* __restrict__ t1h) {
  int idx = blockIdx.x * 256 + threadIdx.x;
  if (idx >= NC1 * 10000) return;
  int c1 = idx / 10000, p = idx % 10000;
  int i = p / 100, j = p % 100;
  float acc = b1[c1];
  for (int dy = 0; dy < 3; ++dy) {
    int yy = i + dy - 1;
    if (yy < 0 || yy >= 100) continue;
    for (int dx = 0; dx < 3; ++dx) {
      int xx = j + dx - 1;
      if (xx < 0 || xx >= 100) continue;
      acc += w1[((c1 * 2 + 0) * 3 + dy) * 3 + dx] * hy[yy] * hx[xx];
    }
  }
  t1h[idx] = acc;
}

__global__ __launch_bounds__(256) void k_t2h(
    const float* __restrict__ w2, const float* __restrict__ b2,
    const float* __restrict__ t1h, float* __restrict__ t2h) {
  int idx = blockIdx.x * 256 + threadIdx.x;
  if (idx >= NC2 * 10000) return;
  int c2 = idx / 10000, p = idx % 10000;
  int i = p / 100, j = p % 100;
  float acc = b2[c2];
  for (int c1 = 0; c1 < NC1; ++c1)
    for (int dy = 0; dy < 3; ++dy) {
      int yy = i + dy - 1;
      if (yy < 0 || yy >= 100) continue;
      for (int dx = 0; dx < 3; ++dx) {
        int xx = j + dx - 1;
        if (xx < 0 || xx >= 100) continue;
        acc += w2[((c2 * NC1 + c1) * 9 + dy * 3 + dx)] *
               t1h[c1 * 10000 + yy * 100 + xx];
      }
    }
  t2h[idx] = acc;
}

// ---------------------------------------------------------------------------
// Composed 5x5 adjoint over proj rows, fused with base-dot and rim extraction.
// grid: (3 row-tiles of 40, 256 features). Threads: 25 colgroups x 10 rowgroups.
// Each thread: 4 rows x 4 cols of G.
__global__ __launch_bounds__(256) void k_adj5(
    const float* __restrict__ P, const float* __restrict__ Weff,
    const float* __restrict__ t2h, float* __restrict__ G,
    float* __restrict__ base, float* __restrict__ rimbuf) {
  __shared__ float tile[44 * 108];
  int tid = threadIdx.x;
  int f = blockIdx.y;
  int R0 = blockIdx.x * 40;
  int rowg = tid / 25;  // 0..10 (250 active)
  int colg = tid % 25;
  bool act = rowg < 10;
  float acc[4][4] = {};
  float bacc = 0.f;
  const float* Pf = P + (size_t)f * (NC2 * 10000);

  for (int c2 = 0; c2 < NC2; ++c2) {
    __syncthreads();
    for (int idx = tid; idx < 44 * 108; idx += 256) {
      int r = idx / 108, c = idx % 108;
      int gr = R0 - 2 + r, gc = c - 2;
      float v = 0.f;
      if (gr >= 0 && gr < 100 && gc >= 0 && gc < 100)
        v = Pf[c2 * 10000 + gr * 100 + gc];
      tile[idx] = v;
    }
    __syncthreads();
    // rim extraction (rows 0/99, cols 0/99 of P) into rimbuf[f][c2][4][100]
    int rb = (f * NC2 + c2) * 400;
    if (R0 == 0 && tid < 100) rimbuf[rb + 0 * 100 + tid] = tile[2 * 108 + tid + 2];
    if (R0 == 80 && tid < 100) rimbuf[rb + 1 * 100 + tid] = tile[21 * 108 + tid + 2];
    if (tid < 40) {
      int gr = R0 + tid;
      if (gr < 100) {
        rimbuf[rb + 2 * 100 + gr] = tile[(tid + 2) * 108 + 2];
        rimbuf[rb + 3 * 100 + gr] = tile[(tid + 2) * 108 + 101];
      }
    }
    if (act) {
      int base_r = rowg * 4;
      const float* We = Weff + c2 * 25;
#pragma unroll
      for (int ir = 0; ir < 8; ++ir) {
        const float* trp = &tile[(base_r + ir) * 108 + colg * 4];
        float row[8];
        *(float4*)&row[0] = *(const float4*)&trp[0];
        *(float4*)&row[4] = *(const float4*)&trp[4];
#pragma unroll
        for (int rr = 0; rr < 4; ++rr) {
          int dy = ir - rr;
          if (dy < 0 || dy > 4) continue;
#pragma unroll
          for (int dx = 0; dx < 5; ++dx)
#pragma unroll
            for (int cc = 0; cc < 4; ++cc)
              acc[rr][cc] += We[dy * 5 + dx] * row[dx + cc];
          if (dy == 2) {
            int grow = R0 + base_r + rr;
            if (grow < 100) {
#pragma unroll
              for (int cc = 0; cc < 4; ++cc)
                bacc += row[cc + 2] *
                        t2h[c2 * 10000 + grow * 100 + colg * 4 + cc];
            }
          }
        }
      }
    }
  }
  if (act) {
#pragma unroll
    for (int rr = 0; rr < 4; ++rr) {
      int grow = R0 + rowg * 4 + rr;
      if (grow < 100)
        *(float4*)&G[(size_t)f * 10000 + grow * 100 + colg * 4] =
            *(const float4*)&acc[rr][0];
    }
  }
  __syncthreads();
  tile[tid] = bacc;
  __syncthreads();
  for (int s = 128; s > 0; s >>= 1) {
    if (tid < s) tile[tid] += tile[tid + s];
    __syncthreads();
  }
  if (tid == 0) atomicAdd(&base[f], tile[0]);
}

// ---------------------------------------------------------------------------
// Exact rim correction: subtract phantom-intermediate contributions on the
// 1-px border. One block per feature.
__global__ __launch_bounds__(256) void k_rim(
    const float* __restrict__ rimbuf, const float* __restrict__ w1,
    const float* __restrict__ w2, float* __restrict__ G) {
  __shared__ float rimh[12800];  // P rim data, later overlaid with h[16][404]
  __shared__ float w1s[288];
  int tid = threadIdx.x;
  int f = blockIdx.x;
  for (int i = tid; i < 12800; i += 256)
    rimh[i] = rimbuf[(size_t)f * 12800 + i];
  for (int i = tid; i < 288; i += 256) w1s[i] = w1[i];
  __syncthreads();

  // h[c1][j] for the 404 phantom intermediate pixels; 2 phantoms per thread.
  float hA[NC1], hB[NC1];
#pragma unroll
  for (int c = 0; c < NC1; ++c) { hA[c] = 0.f; hB[c] = 0.f; }
  int j1 = tid, j2 = tid + 256;
#pragma unroll 1
  for (int c2 = 0; c2 < NC2; ++c2) {
    for (int ty = 0; ty < 3; ++ty)
      for (int tx = 0; tx < 3; ++tx) {
        // weights (uniform -> scalar loads)
        float wv[NC1];
#pragma unroll
        for (int c1 = 0; c1 < NC1; ++c1)
          wv[c1] = w2[(c2 * NC1 + c1) * 9 + (2 - ty) * 3 + (2 - tx)];
        for (int which = 0; which < 2; ++which) {
          int j = which ? j2 : j1;
          if (j >= 404) continue;
          int qy, qx;
          if (j < 102) { qy = -1; qx = j - 1; }
          else if (j < 204) { qy = 100; qx = j - 103; }
          else if (j < 304) { qy = j - 204; qx = -1; }
          else { qy = j - 304; qx = 100; }
          int r = qy + ty - 1, c = qx + tx - 1;
          bool ok = (r >= 0 && r < 100 && c >= 0 && c < 100);
          int side, i;
          if (r == 0) { side = 0; i = c; }
          else if (r == 99) { side = 1; i = c; }
          else if (c == 0) { side = 2; i = r; }
          else { side = 3; i = r; }
          i = min(max(i, 0), 99);
          float val = ok ? rimh[c2 * 400 + side * 100 + i] : 0.f;
          if (which) {
#pragma unroll
            for (int c1 = 0; c1 < NC1; ++c1) hB[c1] += wv[c1] * val;
          } else {
#pragma unroll
            for (int c1 = 0; c1 < NC1; ++c1) hA[c1] += wv[c1] * val;
          }
        }
      }
  }
  __syncthreads();  // done reading rim data
#pragma unroll
  for (int c1 = 0; c1 < NC1; ++c1) {
    if (j1 < 404) rimh[c1 * 404 + j1] = hA[c1];
    if (j2 < 404) rimh[c1 * 404 + j2] = hB[c1];
  }
  __syncthreads();

  // border pixels: subtract phantom terms
  for (int idx = tid; idx < 396; idx += 256) {
    int py, px;
    if (idx < 100) { py = 0; px = idx; }
    else if (idx < 200) { py = 99; px = idx - 100; }
    else if (idx < 298) { py = idx - 199; px = 0; }
    else { py = idx - 297; px = 99; }
    float corr = 0.f;
    for (int sy = 0; sy < 3; ++sy)
      for (int sx = 0; sx < 3; ++sx) {
        int qy = py + sy - 1, qx = px + sx - 1;
        bool ph = (qy == -1 || qy == 100 || qx == -1 || qx == 100);
        if (!ph) continue;
        int j;
        if (qy == -1) j = qx + 1;
        else if (qy == 100) j = 102 + qx + 1;
        else if (qx == -1) j = 204 + qy;
        else j = 304 + qy;
#pragma unroll
        for (int c1 = 0; c1 < NC1; ++c1)
          corr += w1s[((c1 * 2 + 1) * 3 + (2 - sy)) * 3 + (2 - sx)] *
                  rimh[c1 * 404 + j];
      }
    G[(size_t)f * 10000 + py * 100 + px] -= corr;
  }
}

// ---------------------------------------------------------------------------
__global__ __launch_bounds__(256) void k_outinit(
    const float* __restrict__ base, float* __restrict__ out) {
  out[blockIdx.x * 256 + threadIdx.x] = base[threadIdx.x];
}

// out[n,f] += sum_p G[f,p]*py[n,pi]*px[n,pj]. 64x64 tile, split-K=25.
__global__ __launch_bounds__(256) void k_gemm(
    const float* __restrict__ G, const float* __restrict__ pyT,
    const float* __restrict__ pxT, float* __restrict__ out) {
  __shared__ float Gs[16 * 68];
  __shared__ float Ms[16 * 64];
  int tid = threadIdx.x;
  int tf = tid / 16, tn = tid % 16;
  int f0 = blockIdx.x * 64, n0 = blockIdx.y * 64;
  int kbase = blockIdx.z * 400;
  float acc[4][4] = {};
  int fG = tid >> 2, k4 = (tid & 3) * 4;
  for (int ch = 0; ch < 25; ++ch) {
    int kb = kbase + ch * 16;
    __syncthreads();
    {
      float4 g4 = *(const float4*)&G[(size_t)(f0 + fG) * 10000 + kb + k4];
      Gs[(k4 + 0) * 68 + fG] = g4.x;
      Gs[(k4 + 1) * 68 + fG] = g4.y;
      Gs[(k4 + 2) * 68 + fG] = g4.z;
      Gs[(k4 + 3) * 68 + fG] = g4.w;
    }
#pragma unroll
    for (int t = 0; t < 4; ++t) {
      int idx = tid + t * 256;
      int k = idx >> 6, nl = idx & 63;
      int p = kb + k;
      int pi = p / 100, pj = p % 100;
      Ms[k * 64 + nl] = pyT[pi * 256 + n0 + nl] * pxT[pj * 256 + n0 + nl];
    }
    __syncthreads();
#pragma unroll
    for (int k = 0; k < 16; ++k) {
      float4 g = *(const float4*)&Gs[k * 68 + tf * 4];
      float4 m = *(const float4*)&Ms[k * 64 + tn * 4];
      acc[0][0] += g.x * m.x; acc[0][1] += g.x * m.y;
      acc[0][2] += g.x * m.z; acc[0][3] += g.x * m.w;
      acc[1][0] += g.y * m.x; acc[1][1] += g.y * m.y;
      acc[1][2] += g.y * m.z; acc[1][3] += g.y * m.w;
      acc[2][0] += g.z * m.x; acc[2][1] += g.z * m.y;
      acc[2][2] += g.z * m.z; acc[2][3] += g.z * m.w;
      acc[3][0] += g.w * m.x; acc[3][1] += g.w * m.y;
      acc[3][2] += g.w * m.z; acc[3][3] += g.w * m.w;
    }
  }
#pragma unroll
  for (int a = 0; a < 4; ++a)
#pragma unroll
    for (int b = 0; b < 4; ++b)
      atomicAdd(&out[(size_t)(n0 + tn * 4 + b) * 256 + f0 + tf * 4 + a],
                acc[a][b]);
}

// ---------------------------------------------------------------------------
extern "C" void kernel_launch(void* const* d_in, const int* in_sizes, int n_in,
                              void* d_out, int out_size, void* d_ws,
                              size_t ws_size, hipStream_t stream) {
  const int* obj_x = (const int*)d_in[0];
  const int* obj_y = (const int*)d_in[1];
  const int* obj_w = (const int*)d_in[2];
  const int* obj_h = (const int*)d_in[3];
  const int* g_h = (const int*)d_in[4];
  const int* g_w = (const int*)d_in[5];
  const float* conv1_w = (const float*)d_in[6];
  const float* conv1_b = (const float*)d_in[7];
  const float* conv2_w = (const float*)d_in[8];
  const float* conv2_b = (const float*)d_in[9];
  const float* proj_w = (const float*)d_in[10];
  const float* proj_b = (const float*)d_in[11];
  float* out = (float*)d_out;

  float* w = (float*)d_ws;
  float* pyT = w;    w += 100 * 256;
  float* pxT = w;    w += 100 * 256;
  float* hy = w;     w += 100;
  float* hx = w;     w += 100;
  float* t1h = w;    w += NC1 * 10000;
  float* t2h = w;    w += NC2 * 10000;
  float* base = w;   w += NF;
  float* Weff = w;   w += NC2 * 25;
  float* G = w;      w += (size_t)NF * 10000;
  float* rimbuf = w; w += (size_t)NF * NC2 * 400;  // ~25.5 MB total

  k_prep<<<3, 256, 0, stream>>>(obj_x, obj_y, obj_w, obj_h, g_h, g_w, conv1_w,
                                conv2_w, proj_b, pyT, pxT, hy, hx, Weff, base);
  k_t1h<<<625, 256, 0, stream>>>(conv1_w, conv1_b, hy, hx, t1h);
  k_t2h<<<1250, 256, 0, stream>>>(conv2_w, conv2_b, t1h, t2h);
  k_adj5<<<dim3(3, 256), 256, 0, stream>>>(proj_w, Weff, t2h, G, base, rimbuf);
  k_rim<<<256, 256, 0, stream>>>(rimbuf, conv1_w, conv2_w, G);
  k_outinit<<<256, 256, 0, stream>>>(base, out);
  k_gemm<<<dim3(4, 4, 25), 256, 0, stream>>>(G, pyT, pxT, out);
}

// Round 3
// 724.510 us; speedup vs baseline: 2.1051x; 1.3707x over previous
//
#include <hip/hip_runtime.h>
#include <cstddef>

#define NS 256
#define NF 256
#define NC1 16
#define NC2 32

// ---------------------------------------------------------------------------
// prep: block 0 = 1-D bilinear profiles (transposed layout), block 1 = Weff
// (composed 5x5 adjoint kernel), block 2 = base init with proj_b.
__global__ __launch_bounds__(256) void k_prep(
    const int* __restrict__ obx, const int* __restrict__ oby,
    const int* __restrict__ obw, const int* __restrict__ obh,
    const int* __restrict__ ghp, const int* __restrict__ gwp,
    const float* __restrict__ w1, const float* __restrict__ w2,
    const float* __restrict__ pb,
    float* __restrict__ pyT, float* __restrict__ pxT,
    float* __restrict__ hy, float* __restrict__ hx,
    float* __restrict__ Weff, float* __restrict__ base) {
  int tid = threadIdx.x;
  if (blockIdx.x == 0) {
    int n = tid;
    float gh = (float)ghp[0], gw = (float)gwp[0];
    float sy = gh / 100.0f, sx = gw / 100.0f;
    int x0 = obx[n], y0 = oby[n], w = obw[n], h = obh[n];
    for (int j = 0; j < 100; ++j) {
      float u = (j + 0.5f) * sx - 0.5f;
      int a0 = (int)floorf(u);
      float t = u - (float)a0;
      float v0 = (a0 >= x0 && a0 < x0 + w) ? 1.f : 0.f;
      float v1 = (a0 + 1 >= x0 && a0 + 1 < x0 + w) ? 1.f : 0.f;
      pxT[j * 256 + n] = (1.f - t) * v0 + t * v1;
      u = (j + 0.5f) * sy - 0.5f;
      a0 = (int)floorf(u);
      t = u - (float)a0;
      v0 = (a0 >= y0 && a0 < y0 + h) ? 1.f : 0.f;
      v1 = (a0 + 1 >= y0 && a0 + 1 < y0 + h) ? 1.f : 0.f;
      pyT[j * 256 + n] = (1.f - t) * v0 + t * v1;
    }
    if (n < 100) {
      int j = n;
      float u = (j + 0.5f) * sx - 0.5f;
      int a0 = (int)floorf(u);
      float t = u - (float)a0;
      float v0 = (a0 >= 0 && a0 < 100) ? 1.f : 0.f;
      float v1 = (a0 + 1 >= 0 && a0 + 1 < 100) ? 1.f : 0.f;
      hx[j] = (1.f - t) * v0 + t * v1;
      u = (j + 0.5f) * sy - 0.5f;
      a0 = (int)floorf(u);
      t = u - (float)a0;
      v0 = (a0 >= 0 && a0 < 100) ? 1.f : 0.f;
      v1 = (a0 + 1 >= 0 && a0 + 1 < 100) ? 1.f : 0.f;
      hy[j] = (1.f - t) * v0 + t * v1;
    }
  } else if (blockIdx.x == 1) {
    for (int idx = tid; idx < NC2 * 25; idx += 256) {
      int c2 = idx / 25, d = idx % 25;
      int dy = d / 5, dx = d % 5;
      float s = 0.f;
      for (int c1 = 0; c1 < NC1; ++c1)
        for (int sy = 0; sy < 3; ++sy) {
          int ty = dy - sy;
          if (ty < 0 || ty > 2) continue;
          for (int sx = 0; sx < 3; ++sx) {
            int tx = dx - sx;
            if (tx < 0 || tx > 2) continue;
            s += w1[((c1 * 2 + 1) * 3 + (2 - sy)) * 3 + (2 - sx)] *
                 w2[((c2 * NC1 + c1) * 9 + (2 - ty) * 3 + (2 - tx))];
          }
        }
      Weff[idx] = s;
    }
  } else {
    base[tid] = pb[tid];
  }
}

// ---------------------------------------------------------------------------
// Forward human-channel pipeline (with biases).
__global__ __launch_bounds__(256) void k_t1h(
    const float* __restrict__ w1, const float* __restrict__ b1,
    const float* __restrict__ hy, const float* __restrict__ hx,
    float* __restrict__ t1h) {
  int idx = blockIdx.x * 256 + threadIdx.x;
  if (idx >= NC1 * 10000) return;
  int c1 = idx / 10000, p = idx % 10000;
  int i = p / 100, j = p % 100;
  float acc = b1[c1];
  for (int dy = 0; dy < 3; ++dy) {
    int yy = i + dy - 1;
    if (yy < 0 || yy >= 100) continue;
    for (int dx = 0; dx < 3; ++dx) {
      int xx = j + dx - 1;
      if (xx < 0 || xx >= 100) continue;
      acc += w1[((c1 * 2 + 0) * 3 + dy) * 3 + dx] * hy[yy] * hx[xx];
    }
  }
  t1h[idx] = acc;
}

__global__ __launch_bounds__(256) void k_t2h(
    const float* __restrict__ w2, const float* __restrict__ b2,
    const float* __restrict__ t1h, float* __restrict__ t2h) {
  int idx = blockIdx.x * 256 + threadIdx.x;
  if (idx >= NC2 * 10000) return;
  int c2 = idx / 10000, p = idx % 10000;
  int i = p / 100, j = p % 100;
  float acc = b2[c2];
  for (int c1 = 0; c1 < NC1; ++c1)
    for (int dy = 0; dy < 3; ++dy) {
      int yy = i + dy - 1;
      if (yy < 0 || yy >= 100) continue;
      for (int dx = 0; dx < 3; ++dx) {
        int xx = j + dx - 1;
        if (xx < 0 || xx >= 100) continue;
        acc += w2[((c2 * NC1 + c1) * 9 + dy * 3 + dx)] *
               t1h[c1 * 10000 + yy * 100 + xx];
      }
    }
  t2h[idx] = acc;
}

// ---------------------------------------------------------------------------
// Composed 5x5 adjoint over proj rows. 20-row tiles, double-buffered LDS,
// float4 staging, rim extraction and base-dot fused.
// grid (5 row-tiles, 256 f). Thread: rowg=tid/25 (2 rows), colg=tid%25 (4 cols).
// LDS tile layout: 24 rows x 116 stride; interior col gc -> 4+gc; halo cols and
// invalid halo rows are zeroed ONCE (they never change across c2).
__global__ __launch_bounds__(256) void k_adj5(
    const float* __restrict__ P, const float* __restrict__ Weff,
    const float* __restrict__ t2h, float* __restrict__ G,
    float* __restrict__ base, float* __restrict__ rimbuf) {
  __shared__ __align__(16) float buf[2][24 * 116];
  int tid = threadIdx.x;
  int f = blockIdx.y;
  int r0 = blockIdx.x * 20;
  const float* Pf = P + (size_t)f * (NC2 * 10000);
  float* rimf = rimbuf + (size_t)f * (NC2 * 400);

  auto stage = [&](float* b, int c2) {
    const float* Pc = Pf + c2 * 10000;
    float* rimc = rimf + c2 * 400;
    for (int w = tid; w < 600; w += 256) {
      int row = w / 25, k = w % 25;
      int gr = r0 - 2 + row;
      if (gr >= 0 && gr < 100) {
        float4 val = *(const float4*)(Pc + gr * 100 + k * 4);
        *(float4*)(b + row * 116 + 4 + k * 4) = val;
        if (gr == 0) *(float4*)(rimc + k * 4) = val;
        if (gr == 99) *(float4*)(rimc + 100 + k * 4) = val;
        if (k == 0) rimc[200 + gr] = val.x;
        if (k == 24) rimc[300 + gr] = val.w;
      }
    }
  };

  for (int i = tid; i < 2 * 24 * 116; i += 256) ((float*)buf)[i] = 0.f;
  __syncthreads();
  stage(buf[0], 0);

  int rowg = tid / 25, colg = tid % 25;
  bool act = rowg < 10;
  float acc[2][4] = {};
  float bacc = 0.f;

  for (int c2 = 0; c2 < NC2; ++c2) {
    __syncthreads();
    if (c2 + 1 < NC2) stage(buf[(c2 + 1) & 1], c2 + 1);
    if (act) {
      const float* lp = &buf[c2 & 1][rowg * 232 + colg * 4];
      const float* We = Weff + c2 * 25;
#pragma unroll
      for (int ir = 0; ir < 6; ++ir) {
        float4 A = *(const float4*)(lp + ir * 116);
        float4 Bv = *(const float4*)(lp + ir * 116 + 4);
        float4 Cv = *(const float4*)(lp + ir * 116 + 8);
        float v[12] = {A.x,  A.y,  A.z,  A.w,  Bv.x, Bv.y,
                       Bv.z, Bv.w, Cv.x, Cv.y, Cv.z, Cv.w};
#pragma unroll
        for (int rr = 0; rr < 2; ++rr) {
          int dy = ir - rr;
          if (dy < 0 || dy > 4) continue;
#pragma unroll
          for (int dx = 0; dx < 5; ++dx) {
            float w = We[dy * 5 + dx];
#pragma unroll
            for (int cc = 0; cc < 4; ++cc) acc[rr][cc] += w * v[2 + dx + cc];
          }
          if (dy == 2) {
            int grow = r0 + rowg * 2 + rr;
            float4 t =
                *(const float4*)(t2h + c2 * 10000 + grow * 100 + colg * 4);
            bacc += t.x * v[4] + t.y * v[5] + t.z * v[6] + t.w * v[7];
          }
        }
      }
    }
  }
  if (act) {
#pragma unroll
    for (int rr = 0; rr < 2; ++rr) {
      int grow = r0 + rowg * 2 + rr;
      *(float4*)&G[(size_t)f * 10000 + grow * 100 + colg * 4] =
          *(float4*)&acc[rr][0];
    }
  }
  __syncthreads();
  float* red = &buf[0][0];
  red[tid] = bacc;
  __syncthreads();
  for (int s = 128; s > 0; s >>= 1) {
    if (tid < s) red[tid] += red[tid + s];
    __syncthreads();
  }
  if (tid == 0) atomicAdd(&base[f], red[0]);
}

// ---------------------------------------------------------------------------
// Rim stage 1: partial h over c2 quarters. grid (4, 256 f).
__global__ __launch_bounds__(256) void k_rim_h(
    const float* __restrict__ rimbuf, const float* __restrict__ w2,
    float* __restrict__ hpart) {
  __shared__ float rs[8 * 400];
  int tid = threadIdx.x;
  int c2g = blockIdx.x;
  int f = blockIdx.y;
  for (int i = tid; i < 3200; i += 256)
    rs[i] = rimbuf[(size_t)f * 12800 + c2g * 3200 + i];
  __syncthreads();
  for (int qq = 0; qq < 2; ++qq) {
    int j = tid + qq * 256;
    if (j >= 404) break;
    int qy, qx;
    if (j < 102) { qy = -1; qx = j - 1; }
    else if (j < 204) { qy = 100; qx = j - 103; }
    else if (j < 304) { qy = j - 204; qx = -1; }
    else { qy = j - 304; qx = 100; }
    float hacc[NC1];
#pragma unroll
    for (int c1 = 0; c1 < NC1; ++c1) hacc[c1] = 0.f;
    for (int c2l = 0; c2l < 8; ++c2l) {
      int c2 = c2g * 8 + c2l;
      for (int ty = 0; ty < 3; ++ty)
        for (int tx = 0; tx < 3; ++tx) {
          int r = qy + ty - 1, c = qx + tx - 1;
          bool ok = (r >= 0 && r < 100 && c >= 0 && c < 100);
          int side, i2;
          if (r == 0) { side = 0; i2 = c; }
          else if (r == 99) { side = 1; i2 = c; }
          else if (c == 0) { side = 2; i2 = r; }
          else { side = 3; i2 = r; }
          i2 = min(max(i2, 0), 99);
          float val = ok ? rs[c2l * 400 + side * 100 + i2] : 0.f;
#pragma unroll
          for (int c1 = 0; c1 < NC1; ++c1)
            hacc[c1] += w2[(c2 * NC1 + c1) * 9 + (2 - ty) * 3 + (2 - tx)] * val;
        }
    }
#pragma unroll
    for (int c1 = 0; c1 < NC1; ++c1)
      hpart[(((size_t)f * 4 + c2g) * NC1 + c1) * 404 + j] = hacc[c1];
  }
}

// Rim stage 2: sum partials, apply border correction. grid (256 f).
__global__ __launch_bounds__(256) void k_rim_apply(
    const float* __restrict__ hpart, const float* __restrict__ w1,
    float* __restrict__ G) {
  __shared__ float hs[NC1 * 404];
  __shared__ float w1s[288];
  int tid = threadIdx.x;
  int f = blockIdx.x;
  for (int i = tid; i < NC1 * 404; i += 256) {
    float s = 0.f;
    for (int g = 0; g < 4; ++g)
      s += hpart[((size_t)f * 4 + g) * (NC1 * 404) + i];
    hs[i] = s;
  }
  for (int i = tid; i < 288; i += 256) w1s[i] = w1[i];
  __syncthreads();
  for (int idx = tid; idx < 396; idx += 256) {
    int py, px;
    if (idx < 100) { py = 0; px = idx; }
    else if (idx < 200) { py = 99; px = idx - 100; }
    else if (idx < 298) { py = idx - 199; px = 0; }
    else { py = idx - 297; px = 99; }
    float corr = 0.f;
    for (int sy = 0; sy < 3; ++sy)
      for (int sx = 0; sx < 3; ++sx) {
        int qy = py + sy - 1, qx = px + sx - 1;
        bool ph = (qy == -1 || qy == 100 || qx == -1 || qx == 100);
        if (!ph) continue;
        int j;
        if (qy == -1) j = qx + 1;
        else if (qy == 100) j = 103 + qx;
        else if (qx == -1) j = 204 + qy;
        else j = 304 + qy;
#pragma unroll
        for (int c1 = 0; c1 < NC1; ++c1)
          corr += w1s[((c1 * 2 + 1) * 3 + (2 - sy)) * 3 + (2 - sx)] *
                  hs[c1 * 404 + j];
      }
    G[(size_t)f * 10000 + py * 100 + px] -= corr;
  }
}

// ---------------------------------------------------------------------------
// GEMM: part[kS][nT][fT][128n][128f] = sum over 80 k of M[k,n]*G[f,k].
// grid (2 fT, 2 nT, 125 kS).
__global__ __launch_bounds__(256) void k_gemm(
    const float* __restrict__ G, const float* __restrict__ pyT,
    const float* __restrict__ pxT, float* __restrict__ part) {
  __shared__ float Gs[8 * 132];
  __shared__ float Ms[8 * 128];
  int tid = threadIdx.x;
  int fT = blockIdx.x, nT = blockIdx.y, kS = blockIdx.z;
  int f0 = fT * 128, n0 = nT * 128, kb0 = kS * 80;
  int tf = tid % 16, tn = tid / 16;
  int fG = tid >> 1, kq = (tid & 1) * 4;
  int nl = tid & 127, kh = tid >> 7;
  float acc[8][8] = {};
  for (int ch = 0; ch < 10; ++ch) {
    int kb = kb0 + ch * 8;
    __syncthreads();
    {
      float4 g = *(const float4*)&G[(size_t)(f0 + fG) * 10000 + kb + kq];
      Gs[(kq + 0) * 132 + fG] = g.x;
      Gs[(kq + 1) * 132 + fG] = g.y;
      Gs[(kq + 2) * 132 + fG] = g.z;
      Gs[(kq + 3) * 132 + fG] = g.w;
    }
#pragma unroll
    for (int kk = 0; kk < 4; ++kk) {
      int k = kh * 4 + kk;
      int p = kb + k;
      int pi = p / 100, pj = p - pi * 100;
      Ms[k * 128 + nl] = pyT[pi * 256 + n0 + nl] * pxT[pj * 256 + n0 + nl];
    }
    __syncthreads();
#pragma unroll
    for (int k = 0; k < 8; ++k) {
      float4 ga = *(const float4*)&Gs[k * 132 + tf * 8];
      float4 gb = *(const float4*)&Gs[k * 132 + tf * 8 + 4];
      float4 ma = *(const float4*)&Ms[k * 128 + tn * 8];
      float4 mb = *(const float4*)&Ms[k * 128 + tn * 8 + 4];
      float gv[8] = {ga.x, ga.y, ga.z, ga.w, gb.x, gb.y, gb.z, gb.w};
      float mv[8] = {ma.x, ma.y, ma.z, ma.w, mb.x, mb.y, mb.z, mb.w};
#pragma unroll
      for (int nn = 0; nn < 8; ++nn)
#pragma unroll
        for (int ff = 0; ff < 8; ++ff) acc[nn][ff] += mv[nn] * gv[ff];
    }
  }
  size_t pb = (((size_t)kS * 2 + nT) * 2 + fT) * 16384;
#pragma unroll
  for (int nn = 0; nn < 8; ++nn) {
    int row = tn * 8 + nn;
    *(float4*)&part[pb + row * 128 + tf * 8] =
        make_float4(acc[nn][0], acc[nn][1], acc[nn][2], acc[nn][3]);
    *(float4*)&part[pb + row * 128 + tf * 8 + 4] =
        make_float4(acc[nn][4], acc[nn][5], acc[nn][6], acc[nn][7]);
  }
}

// Reduce split-K partials + base into out[n,f].
__global__ __launch_bounds__(256) void k_out(
    const float* __restrict__ part, const float* __restrict__ base,
    float* __restrict__ out) {
  int gid = blockIdx.x * 256 + threadIdx.x;
  int f = gid & 255, n = gid >> 8;
  int nT = n >> 7, nl = n & 127, fT = f >> 7, fl = f & 127;
  float val = base[f];
  size_t off = ((size_t)(nT * 2 + fT)) * 16384 + nl * 128 + fl;
  for (int s = 0; s < 125; ++s) val += part[(size_t)s * 65536 + off];
  out[(size_t)n * 256 + f] = val;
}

// ---------------------------------------------------------------------------
extern "C" void kernel_launch(void* const* d_in, const int* in_sizes, int n_in,
                              void* d_out, int out_size, void* d_ws,
                              size_t ws_size, hipStream_t stream) {
  const int* obj_x = (const int*)d_in[0];
  const int* obj_y = (const int*)d_in[1];
  const int* obj_w = (const int*)d_in[2];
  const int* obj_h = (const int*)d_in[3];
  const int* g_h = (const int*)d_in[4];
  const int* g_w = (const int*)d_in[5];
  const float* conv1_w = (const float*)d_in[6];
  const float* conv1_b = (const float*)d_in[7];
  const float* conv2_w = (const float*)d_in[8];
  const float* conv2_b = (const float*)d_in[9];
  const float* proj_w = (const float*)d_in[10];
  const float* proj_b = (const float*)d_in[11];
  float* out = (float*)d_out;

  float* w = (float*)d_ws;
  float* pyT = w;    w += 100 * 256;
  float* pxT = w;    w += 100 * 256;
  float* hy = w;     w += 100;
  float* hx = w;     w += 100;
  float* t1h = w;    w += NC1 * 10000;
  float* t2h = w;    w += NC2 * 10000;
  float* base = w;   w += NF;
  float* Weff = w;   w += NC2 * 25;
  float* G = w;      w += (size_t)NF * 10000;
  float* rimbuf = w; w += (size_t)NF * NC2 * 400;
  float* hpart = w;  w += (size_t)NF * 4 * NC1 * 404;
  float* part = w;   w += (size_t)500 * 16384;  // total ~85 MB

  k_prep<<<3, 256, 0, stream>>>(obj_x, obj_y, obj_w, obj_h, g_h, g_w, conv1_w,
                                conv2_w, proj_b, pyT, pxT, hy, hx, Weff, base);
  k_t1h<<<625, 256, 0, stream>>>(conv1_w, conv1_b, hy, hx, t1h);
  k_t2h<<<1250, 256, 0, stream>>>(conv2_w, conv2_b, t1h, t2h);
  k_adj5<<<dim3(5, 256), 256, 0, stream>>>(proj_w, Weff, t2h, G, base, rimbuf);
  k_rim_h<<<dim3(4, 256), 256, 0, stream>>>(rimbuf, conv2_w, hpart);
  k_rim_apply<<<256, 256, 0, stream>>>(hpart, conv1_w, G);
  k_gemm<<<dim3(2, 2, 125), 256, 0, stream>>>(G, pyT, pxT, part);
  k_out<<<256, 256, 0, stream>>>(part, base, out);
}